// Round 5
// baseline (259.409 us; speedup 1.0000x reference)
//
#include <hip/hip_runtime.h>

typedef unsigned short u16;
typedef unsigned int   u32;
typedef __bf16 bf16x8 __attribute__((ext_vector_type(8)));
typedef float  f32x4  __attribute__((ext_vector_type(4)));
typedef unsigned short u16x8 __attribute__((ext_vector_type(8)));
typedef unsigned short u16x4 __attribute__((ext_vector_type(4)));

#define SEQ 2048
#define DM  1024
#define TOKS 8388608  // 4*2048*1024 elements
#define SCLQ 0.18033688f  // log2(e)/8, folded into Q projection

__device__ __forceinline__ float bf2f(u16 u) {
    u32 i = ((u32)u) << 16;
    float f; __builtin_memcpy(&f, &i, 4); return f;
}
__device__ __forceinline__ u16 f2bf(float f) {
    u32 i; __builtin_memcpy(&i, &f, 4);
    return (u16)((i + 0x7FFFu + ((i >> 16) & 1u)) >> 16);  // RNE
}
__device__ __forceinline__ bf16x8 ld8(const u16* p) {
    return __builtin_bit_cast(bf16x8, *(const u16x8*)p);
}
#define GLD16(src, dst) __builtin_amdgcn_global_load_lds( \
    (const __attribute__((address_space(1))) void*)(src), \
    (__attribute__((address_space(3))) void*)(dst), 16, 0, 0)

// Wave-local dtype sniff: bf16 inputs -> both u16 halves of x words have sane
// exponents (~64/64); fp32 inputs -> low half is mantissa garbage (~10/64).
__device__ __forceinline__ int sniff_fp32(const u32* x) {
    u32 w = x[threadIdx.x & 63];
    int e0 = (int)((w >> 7) & 0xFFu);
    int cnt = (e0 >= 100 && e0 <= 140) ? 1 : 0;
#pragma unroll
    for (int off = 32; off; off >>= 1) cnt += __shfl_xor(cnt, off);
    return cnt < 32;   // 1 = fp32 inputs
}

// ---------------- prep: fused dtype-detect + weight/bias convert + LayerNorm ----
// grid.x: [0,8192) ln rows | [8192,12288) weight convert | 12288 bias vectors+flag
__global__ __launch_bounds__(256) void prep_k(const void* __restrict__ x,
                                              const void* Wq, const void* Wk, const void* Wv, const void* Wo,
                                              const void* bq, const void* bk, const void* bv, const void* bo,
                                              const void* g, const void* b,
                                              u16* __restrict__ dstW, u16* __restrict__ dstV,
                                              u16* __restrict__ xn, int* __restrict__ flagp) {
    const int bid = blockIdx.x, tid = threadIdx.x;
    const int fp32m = sniff_fp32((const u32*)x);

    if (bid < 8192) {
        // ---- LayerNorm row ----
        const int row = bid;
        float f[4], s1 = 0.f, s2 = 0.f;
        if (fp32m) {
            f32x4 v = *(const f32x4*)((const float*)x + (size_t)row * DM + tid * 4);
#pragma unroll
            for (int j = 0; j < 4; ++j) f[j] = v[j];
        } else {
            u16x4 v = *(const u16x4*)((const u16*)x + (size_t)row * DM + tid * 4);
#pragma unroll
            for (int j = 0; j < 4; ++j) f[j] = bf2f(v[j]);
        }
#pragma unroll
        for (int j = 0; j < 4; ++j) { s1 += f[j]; s2 += f[j] * f[j]; }
#pragma unroll
        for (int off = 32; off; off >>= 1) { s1 += __shfl_xor(s1, off); s2 += __shfl_xor(s2, off); }
        __shared__ float red[8];
        const int wave = tid >> 6, lane = tid & 63;
        if (lane == 0) { red[wave] = s1; red[4 + wave] = s2; }
        __syncthreads();
        s1 = red[0] + red[1] + red[2] + red[3];
        s2 = red[4] + red[5] + red[6] + red[7];
        const float mu = s1 * (1.f / DM);
        const float var = s2 * (1.f / DM) - mu * mu;
        const float rs = rsqrtf(var + 1e-5f);
        float gv[4], bv2[4];
        if (fp32m) {
            f32x4 gg = *(const f32x4*)((const float*)g + tid * 4);
            f32x4 bb = *(const f32x4*)((const float*)b + tid * 4);
#pragma unroll
            for (int j = 0; j < 4; ++j) { gv[j] = gg[j]; bv2[j] = bb[j]; }
        } else {
            u16x4 gg = *(const u16x4*)((const u16*)g + tid * 4);
            u16x4 bb = *(const u16x4*)((const u16*)b + tid * 4);
#pragma unroll
            for (int j = 0; j < 4; ++j) { gv[j] = bf2f(gg[j]); bv2[j] = bf2f(bb[j]); }
        }
        u16x4 o;
#pragma unroll
        for (int j = 0; j < 4; ++j) o[j] = f2bf((f[j] - mu) * rs * gv[j] + bv2[j]);
        *(u16x4*)(xn + (size_t)row * DM + tid * 4) = o;
    } else if (bid < 12288) {
        // ---- weight convert (copy if already bf16) ----
        const int wi = (bid - 8192) >> 10, blk = (bid - 8192) & 1023;
        const void* src = (wi == 0) ? Wq : (wi == 1) ? Wk : (wi == 2) ? Wv : Wo;
        const size_t off = (size_t)blk * 1024 + tid * 4;
        u16x4 o;
        if (fp32m) {
            const float* f = (const float*)src + off;
#pragma unroll
            for (int j = 0; j < 4; ++j) o[j] = f2bf(f[j]);
        } else {
            o = *(const u16x4*)((const u16*)src + off);
        }
        *(u16x4*)(dstW + (size_t)wi * 1048576 + off) = o;
    } else {
        // ---- bias vectors + flag ----
#pragma unroll
        for (int i = 0; i < 4; ++i) {
            const void* src = (i == 0) ? bq : (i == 1) ? bk : (i == 2) ? bv : bo;
            u16x4 o;
            if (fp32m) {
                const float* f = (const float*)src + tid * 4;
#pragma unroll
                for (int j = 0; j < 4; ++j) o[j] = f2bf(f[j]);
            } else {
                o = *(const u16x4*)((const u16*)src + tid * 4);
            }
            *(u16x4*)(dstV + (size_t)i * 1024 + tid * 4) = o;
        }
        if (tid == 0) *flagp = fp32m;
    }
}

// ---------------- QKV GEMM core: C[m][j] = (sum_k A[m][k]*W[j][k] + bias[j]) * scale
// 128x128 tile, BK=32, 4 waves each 64x64, global_load_lds width 16 (m97).
template <int VT>
__device__ __forceinline__ void gemm_core(u16* As, u16* Bs,
                                          const u16* __restrict__ A,
                                          const u16* __restrict__ W,
                                          const u16* __restrict__ bias,
                                          u16* __restrict__ out,
                                          float scale) {
    const int tid = threadIdx.x, wave = tid >> 6, lane = tid & 63;
    const int l4 = lane & 15, q4 = lane >> 4;
    const int bm = blockIdx.x, bn = blockIdx.y;
    const int wm = (wave >> 1) * 64, wn = (wave & 1) * 64;
    f32x4 acc[4][4] = {};
    const int srow = wave * 32 + (lane >> 2);
    const int skoff = (lane & 3) * 8;
    const u16* Ag = A + ((size_t)(bm * 128 + srow)) * DM + skoff;
    const u16* Wg = W + ((size_t)(bn * 128 + srow)) * DM + skoff;
    u16* As0 = As + wave * 1024;
    u16* Bs0 = Bs + wave * 1024;

    for (int k0 = 0; k0 < DM; k0 += 32) {
        GLD16(Ag + k0, As0);
        GLD16(Ag + 16 * DM + k0, As0 + 512);
        GLD16(Wg + k0, Bs0);
        GLD16(Wg + 16 * DM + k0, Bs0 + 512);
        __syncthreads();
        bf16x8 af[4], bfr[4];
#pragma unroll
        for (int t = 0; t < 4; ++t)
            af[t] = ld8(As + (wm + t * 16 + l4) * 32 + q4 * 8);
#pragma unroll
        for (int t = 0; t < 4; ++t)
            bfr[t] = ld8(Bs + (wn + t * 16 + l4) * 32 + q4 * 8);
#pragma unroll
        for (int mt = 0; mt < 4; ++mt)
#pragma unroll
            for (int nt = 0; nt < 4; ++nt)
                acc[mt][nt] = __builtin_amdgcn_mfma_f32_16x16x32_bf16(af[mt], bfr[nt], acc[mt][nt], 0, 0, 0);
        __syncthreads();
    }

#pragma unroll
    for (int nt = 0; nt < 4; ++nt) {
        const int col = bn * 128 + wn + nt * 16 + l4;
        const float bs = bf2f(bias[col]);
#pragma unroll
        for (int mt = 0; mt < 4; ++mt) {
            const int row0 = bm * 128 + wm + mt * 16 + q4 * 4;
            if (VT == 1) {
                const int nb = row0 >> 11, s0 = row0 & 2047;
                u16x4 pk;
#pragma unroll
                for (int r = 0; r < 4; ++r) pk[r] = f2bf((acc[mt][nt][r] + bs) * scale);
                *(u16x4*)(out + ((size_t)(nb * 1024 + col)) * SEQ + s0) = pk;
            } else {
#pragma unroll
                for (int r = 0; r < 4; ++r)
                    out[(size_t)(row0 + r) * DM + col] = f2bf((acc[mt][nt][r] + bs) * scale);
            }
        }
    }
}

__global__ __launch_bounds__(256) void gemm_qkv_k(const u16* __restrict__ xn, const u16* __restrict__ Wc,
                                                  const u16* __restrict__ Vc,
                                                  u16* __restrict__ Q, u16* __restrict__ K, u16* __restrict__ Vt) {
    __shared__ alignas(16) u16 As[128 * 32];
    __shared__ alignas(16) u16 Bs[128 * 32];
    const int z = blockIdx.z;
    if (z == 0)      gemm_core<0>(As, Bs, xn, Wc,               Vc,        Q,  SCLQ);
    else if (z == 1) gemm_core<0>(As, Bs, xn, Wc + 1048576,     Vc + 1024, K,  1.0f);
    else             gemm_core<1>(As, Bs, xn, Wc + 2 * 1048576, Vc + 2048, Vt, 1.0f);
}

// ---------------- Output projection GEMM: 512-thread blocks for occupancy ----
// 128x128 tile, 8 waves each own 64x32 (4x2 MFMA tiles); 2 blocks/CU -> 16 waves/CU
// (vs 8 with 256-thread blocks on the 512-block grid). Staging: 2 GLD/wave/iter.
__global__ __launch_bounds__(512) void gemm_out_k(const u16* __restrict__ Z, const u16* __restrict__ Wc,
                                                  const u16* __restrict__ Vc,
                                                  u16* __restrict__ out, const int* __restrict__ flagp) {
    __shared__ alignas(16) u16 As[128 * 32];
    __shared__ alignas(16) u16 Bs[128 * 32];
    const u16* W = Wc + 3 * 1048576;
    const u16* bias = Vc + 3 * 1024;
    const int tid = threadIdx.x, wave = tid >> 6, lane = tid & 63;
    const int l4 = lane & 15, q4 = lane >> 4;
    const int bm = blockIdx.x, bn = blockIdx.y;
    const int wm = (wave >> 2) * 64, wn = (wave & 3) * 32;
    const int fp32m = *flagp;
    f32x4 acc[4][2] = {};
    // staging rows 0..255: A rows 0..127 (waves 0-3), B rows 0..127 (waves 4-7)
    const int srow = (wave & 3) * 32 + (lane >> 2);
    const int skoff = (lane & 3) * 8;
    const u16* Sg = (wave < 4) ? (Z + ((size_t)(bm * 128 + srow)) * DM + skoff)
                               : (W + ((size_t)(bn * 128 + srow)) * DM + skoff);
    u16* dst0 = (wave < 4) ? (As + (wave & 3) * 1024) : (Bs + (wave & 3) * 1024);

    for (int k0 = 0; k0 < DM; k0 += 32) {
        GLD16(Sg + k0, dst0);
        GLD16(Sg + 16 * DM + k0, dst0 + 512);
        __syncthreads();
        bf16x8 af[4], bfr[2];
#pragma unroll
        for (int t = 0; t < 4; ++t)
            af[t] = ld8(As + (wm + t * 16 + l4) * 32 + q4 * 8);
#pragma unroll
        for (int t = 0; t < 2; ++t)
            bfr[t] = ld8(Bs + (wn + t * 16 + l4) * 32 + q4 * 8);
#pragma unroll
        for (int mt = 0; mt < 4; ++mt)
#pragma unroll
            for (int nt = 0; nt < 2; ++nt)
                acc[mt][nt] = __builtin_amdgcn_mfma_f32_16x16x32_bf16(af[mt], bfr[nt], acc[mt][nt], 0, 0, 0);
        __syncthreads();
    }

#pragma unroll
    for (int nt = 0; nt < 2; ++nt) {
        const int col = bn * 128 + wn + nt * 16 + l4;
        const float bs = bf2f(bias[col]);
#pragma unroll
        for (int mt = 0; mt < 4; ++mt) {
            const int row0 = bm * 128 + wm + mt * 16 + q4 * 4;
            if (fp32m) {
#pragma unroll
                for (int r = 0; r < 4; ++r)
                    ((float*)out)[(size_t)(row0 + r) * DM + col] = acc[mt][nt][r] + bs;
            } else {
#pragma unroll
                for (int r = 0; r < 4; ++r)
                    out[(size_t)(row0 + r) * DM + col] = f2bf(acc[mt][nt][r] + bs);
            }
        }
    }
}

// ---------------- Flash attention (causal, fixed-max softmax, LDS-staged K/V) ----
__global__ __launch_bounds__(256, 4) void flash_k(const u16* __restrict__ Q,
                                                  const u16* __restrict__ K,
                                                  const u16* __restrict__ Vt,
                                                  u16* __restrict__ Z) {
    const int bh = blockIdx.x;
    const int qb = 15 - (int)blockIdx.y;       // heavy q-blocks dispatch first
    const int n = bh >> 4, h = bh & 15;
    const int tid = threadIdx.x, wave = tid >> 6, lane = tid & 63;
    const int l4 = lane & 15, q4 = lane >> 4;

    __shared__ alignas(16) u16 Ks[2][64 * 32];   // [k-half][kv][32 dm]
    __shared__ alignas(16) u16 Vs[2][64 * 32];   // [kv-half][d][32 kv]
    __shared__ alignas(16) u16 Pl[4][2][16 * 72];

    const int Q0w = qb * 128 + wave * 32;
    bf16x8 qf[2][2];
#pragma unroll
    for (int qt = 0; qt < 2; ++qt) {
        const u16* Qr = Q + ((size_t)(n * SEQ + Q0w + qt * 16 + l4)) * DM + h * 64 + q4 * 8;
        qf[qt][0] = ld8(Qr);
        qf[qt][1] = ld8(Qr + 32);
    }

    const int srow = lane >> 2, scol = (lane & 3) * 8;
    const u16* Kg = K + ((size_t)(n * SEQ + wave * 16 + srow)) * DM + h * 64 + scol;
    const u16* Vg = Vt + ((size_t)(n * 1024 + h * 64 + wave * 16 + srow)) * SEQ + scol;
    u16* KsD0 = &Ks[0][wave * 512];
    u16* KsD1 = &Ks[1][wave * 512];
    u16* VsD0 = &Vs[0][wave * 512];
    u16* VsD1 = &Vs[1][wave * 512];

    f32x4 o[2][4] = {};
    float l_acc[2] = {0.f, 0.f};
    const int nch = 2 * qb + 2;

    for (int c = 0; c < nch; ++c) {
        const int kv0 = c * 64;
        const size_t krow = (size_t)kv0 * DM;
        GLD16(Kg + krow, KsD0);
        GLD16(Kg + krow + 32, KsD1);
        GLD16(Vg + kv0, VsD0);
        GLD16(Vg + kv0 + 32, VsD1);
        __syncthreads();

        bf16x8 a[4][2];
#pragma unroll
        for (int mt = 0; mt < 4; ++mt) {
            a[mt][0] = ld8(&Ks[0][(mt * 16 + l4) * 32 + q4 * 8]);
            a[mt][1] = ld8(&Ks[1][(mt * 16 + l4) * 32 + q4 * 8]);
        }
#pragma unroll
        for (int qt = 0; qt < 2; ++qt) {
            f32x4 st[4];
#pragma unroll
            for (int mt = 0; mt < 4; ++mt) {
                f32x4 zz = {0.f, 0.f, 0.f, 0.f};
                st[mt] = __builtin_amdgcn_mfma_f32_16x16x32_bf16(a[mt][0], qf[qt][0], zz, 0, 0, 0);
                st[mt] = __builtin_amdgcn_mfma_f32_16x16x32_bf16(a[mt][1], qf[qt][1], st[mt], 0, 0, 0);
            }
            const int qg = Q0w + qt * 16 + l4;
            u16* P = Pl[wave][qt];
            float la = l_acc[qt];
#pragma unroll
            for (int mt = 0; mt < 4; ++mt) {
                __bf16 pk[4];
#pragma unroll
                for (int r = 0; r < 4; ++r) {
                    const int kv = kv0 + mt * 16 + q4 * 4 + r;
                    float p = __builtin_amdgcn_exp2f(st[mt][r]);
                    p = (kv > qg) ? 0.f : p;
                    la += p;
                    pk[r] = (__bf16)p;
                }
                *(u16x4*)(P + l4 * 72 + mt * 16 + q4 * 4) = *(u16x4*)pk;
            }
            l_acc[qt] = la;
        }
#pragma unroll
        for (int ks = 0; ks < 2; ++ks) {
            bf16x8 pf0 = ld8(&Pl[wave][0][l4 * 72 + ks * 32 + q4 * 8]);
            bf16x8 pf1 = ld8(&Pl[wave][1][l4 * 72 + ks * 32 + q4 * 8]);
#pragma unroll
            for (int nt = 0; nt < 4; ++nt) {
                bf16x8 vf = ld8(&Vs[ks][(nt * 16 + l4) * 32 + q4 * 8]);
                o[0][nt] = __builtin_amdgcn_mfma_f32_16x16x32_bf16(pf0, vf, o[0][nt], 0, 0, 0);
                o[1][nt] = __builtin_amdgcn_mfma_f32_16x16x32_bf16(pf1, vf, o[1][nt], 0, 0, 0);
            }
        }
        __syncthreads();
    }

#pragma unroll
    for (int qt = 0; qt < 2; ++qt) {
        float l = l_acc[qt];
        l += __shfl_xor(l, 16);
        l += __shfl_xor(l, 32);
        float lr[4];
#pragma unroll
        for (int r = 0; r < 4; ++r) lr[r] = 1.f / __shfl(l, q4 * 4 + r);
#pragma unroll
        for (int nt = 0; nt < 4; ++nt) {
            const int col = h * 64 + nt * 16 + l4;
#pragma unroll
            for (int r = 0; r < 4; ++r) {
                const int row = n * SEQ + Q0w + qt * 16 + q4 * 4 + r;
                Z[(size_t)row * DM + col] = f2bf(o[qt][nt][r] * lr[r]);
            }
        }
    }
}

extern "C" void kernel_launch(void* const* d_in, const int* in_sizes, int n_in,
                              void* d_out, int out_size, void* d_ws, size_t ws_size,
                              hipStream_t stream) {
    const void* x  = d_in[0];
    const void* Wq = d_in[1];
    const void* bq = d_in[2];
    const void* Wk = d_in[3];
    const void* bk = d_in[4];
    const void* Wv = d_in[5];
    const void* bv = d_in[6];
    const void* Wo = d_in[7];
    const void* bo = d_in[8];
    const void* g  = d_in[9];
    const void* b  = d_in[10];
    u16* ws = (u16*)d_ws;

    u16* xn  = ws;
    u16* Qb  = ws + (size_t)TOKS;
    u16* Kb  = ws + (size_t)2 * TOKS;
    u16* Vtb = ws + (size_t)3 * TOKS;
    u16* Zb  = ws;  // xn dead after qkv gemm
    u16* Wc  = ws + (size_t)4 * TOKS;
    u16* Vc  = Wc + 4 * 1048576;
    int* flagp = (int*)(Vc + 8 * 1024);

    prep_k<<<dim3(12289), 256, 0, stream>>>(x, Wq, Wk, Wv, Wo, bq, bk, bv, bo, g, b, Wc, Vc, xn, flagp);
    gemm_qkv_k<<<dim3(64, 8, 3), 256, 0, stream>>>(xn, Wc, Vc, Qb, Kb, Vtb);
    flash_k<<<dim3(64, 16), 256, 0, stream>>>(Qb, Kb, Vtb, Zb);
    gemm_out_k<<<dim3(64, 8), 512, 0, stream>>>(Zb, Wc, Vc, (u16*)d_out, flagp);
}